// Round 5
// baseline (72.829 us; speedup 1.0000x reference)
//
#include <hip/hip_runtime.h>
#include <math.h>

// Model_78271484002488: B=8, L=512, D=32, N_PATCHES=16, N_REF=32, LAT=128, HM=4,
// FH=8, NL=3, FF=128, PRED=96.  All f32.

#define ISQ32 0.17677669529663687f   // 1/sqrt(32)
#define C128  (-0.07195578415606394f)  // -ln(1e4)/128
#define C32   (-0.28782313662425575f)  // -ln(1e4)/32

// ---------------------------------------------------------------------------
// K0: blocks [0,144): embed matvec, 32 rows/block (8 rows/wave, W read once per
//     wave per k with 8-row reuse -> 8x less L2 traffic than 1 row/wave).
//     blocks [144,656): obsBits via ballot.
__launch_bounds__(256)
__global__ void k_embed_mm(const float* __restrict__ x_mark,
                           const float* __restrict__ Wk,
                           const float* __restrict__ Wq,
                           const float* __restrict__ x_mask,
                           float* __restrict__ Kmat,
                           float* __restrict__ Qall,
                           unsigned* __restrict__ obsBits) {
    if (blockIdx.x >= 144) {
        const int gt = (blockIdx.x - 144) * 256 + threadIdx.x;
        const int w = gt >> 6, lane = gt & 63;
        const int bl = w * 2 + (lane >> 5);
        const int d = lane & 31;
        const unsigned long long mm = __ballot(x_mask[bl * 32 + d] > 0.0f);
        if (lane == 0)  obsBits[w * 2]     = (unsigned)(mm & 0xffffffffull);
        if (lane == 32) obsBits[w * 2 + 1] = (unsigned)(mm >> 32);
        return;
    }
    __shared__ float sTe[32][128];
    const int wv = threadIdx.x >> 6;
    const int lane = threadIdx.x & 63;
    const int bb = blockIdx.x;
    const int row0 = bb * 32 + wv * 8;
    const float dv = __expf((float)(2 * lane) * C128);
    #pragma unroll
    for (int rr = 0; rr < 8; ++rr) {
        const int row = row0 + rr;
        const float t = (row < 4096) ? x_mark[row] : (float)(row - 4096) * (512.0f / 511.0f);
        const float ang = t * dv;
        sTe[wv * 8 + rr][2 * lane]     = __sinf(ang);
        sTe[wv * 8 + rr][2 * lane + 1] = __cosf(ang);
    }
    __syncthreads();
    const float* W = (bb < 128) ? Wk : Wq;
    float a0[8], a1[8];
    #pragma unroll
    for (int rr = 0; rr < 8; ++rr) { a0[rr] = 0.f; a1[rr] = 0.f; }
    for (int k = 0; k < 128; ++k) {
        const float wa = W[k * 128 + lane];
        const float wb = W[k * 128 + lane + 64];
        #pragma unroll
        for (int rr = 0; rr < 8; ++rr) {
            const float te = sTe[wv * 8 + rr][k];   // uniform addr -> broadcast
            a0[rr] = fmaf(te, wa, a0[rr]);
            a1[rr] = fmaf(te, wb, a1[rr]);
        }
    }
    #pragma unroll
    for (int rr = 0; rr < 8; ++rr) {
        const int row = row0 + rr;
        float* outp = (row < 4096) ? (Kmat + row * 128) : (Qall + (row - 4096) * 128);
        outp[lane] = a0[rr];
        outp[lane + 64] = a1[rr];
    }
}

// ---------------------------------------------------------------------------
// K1: fused patch attention, range-based.  block = (i,b,h); 256 threads.
__launch_bounds__(256)
__global__ void k_patch_attn(const float* __restrict__ x,
                             const float* __restrict__ x_mark,
                             const unsigned* __restrict__ obsBits,
                             const float* __restrict__ Kmat,
                             const float* __restrict__ Qall,
                             float* __restrict__ attn) {
    __shared__ float sQ[32][36];
    __shared__ float sK[96][36];
    __shared__ float sX[96][36];
    __shared__ float sS[32][100];
    __shared__ unsigned sBits[96];
    __shared__ int sLo, sHi;
    __shared__ unsigned sAV;
    const int tid = threadIdx.x;
    const int h = blockIdx.x & 3;
    const int b = (blockIdx.x >> 2) & 7;
    const int i = blockIdx.x >> 5;
    const float e0 = 32.0f * (float)i, e1 = 32.0f * (float)(i + 1);
    if (tid == 0) { sLo = 512; sHi = -1; sAV = 0u; }
    __syncthreads();
    #pragma unroll
    for (int k = 0; k < 4; ++k) {
        const int idx = tid + 256 * k;
        sQ[idx >> 5][idx & 31] = Qall[(i * 32 + (idx >> 5)) * 128 + h * 32 + (idx & 31)];
    }
    {
        int mylo = 512, myhi = -1;
        unsigned mybits = 0u;
        #pragma unroll
        for (int k = 0; k < 2; ++k) {
            const int l = tid + 256 * k;
            const float t = x_mark[b * 512 + l];
            if (t >= e0 && t <= e1) {
                mylo = min(mylo, l);
                myhi = max(myhi, l);
                mybits |= obsBits[b * 512 + l];
            }
        }
        #pragma unroll
        for (int off = 32; off > 0; off >>= 1) {
            mylo = min(mylo, __shfl_xor(mylo, off));
            myhi = max(myhi, __shfl_xor(myhi, off));
            mybits |= __shfl_xor(mybits, off);
        }
        if ((tid & 63) == 0) {
            atomicMin(&sLo, mylo);
            atomicMax(&sHi, myhi);
            atomicOr(&sAV, mybits);
        }
    }
    __syncthreads();
    const int lo = sLo, hi = sHi;
    const int NA = hi - lo + 1;
    const unsigned av = sAV;
    const int r = tid >> 3, dg = tid & 7;

    if (NA >= 1 && NA <= 96 && av == 0xffffffffu) {
        if (tid < NA) sBits[tid] = obsBits[b * 512 + lo + tid];
        for (int idx = tid; idx < NA * 32; idx += 256) {
            const int ll = idx >> 5, c = idx & 31;
            sK[ll][c] = Kmat[(b * 512 + lo + ll) * 128 + h * 32 + c];
            sX[ll][c] = x[(b * 512 + lo + ll) * 32 + c];
        }
        __syncthreads();
        float m = -1e30f;
        for (int ll = dg; ll < NA; ll += 8) {
            float p0 = 0.f, p1 = 0.f, p2 = 0.f, p3 = 0.f;
            #pragma unroll
            for (int e = 0; e < 32; e += 4) {
                p0 = fmaf(sQ[r][e],     sK[ll][e],     p0);
                p1 = fmaf(sQ[r][e + 1], sK[ll][e + 1], p1);
                p2 = fmaf(sQ[r][e + 2], sK[ll][e + 2], p2);
                p3 = fmaf(sQ[r][e + 3], sK[ll][e + 3], p3);
            }
            const float s = (p0 + p1 + p2 + p3) * ISQ32;
            sS[r][ll] = s;
            m = fmaxf(m, s);
        }
        #pragma unroll
        for (int off = 4; off > 0; off >>= 1) m = fmaxf(m, __shfl_xor(m, off));
        for (int ll = dg; ll < NA; ll += 8) sS[r][ll] = __expf(sS[r][ll] - m);
        __syncthreads();
        float num0 = 0.f, num1 = 0.f, num2 = 0.f, num3 = 0.f;
        float den0 = 0.f, den1 = 0.f, den2 = 0.f, den3 = 0.f;
        for (int ll = 0; ll < NA; ++ll) {
            const float e = sS[r][ll];
            const unsigned bits = sBits[ll];
            if ((bits >> dg) & 1u)        { den0 += e; num0 = fmaf(e, sX[ll][dg],      num0); }
            if ((bits >> (dg + 8)) & 1u)  { den1 += e; num1 = fmaf(e, sX[ll][dg + 8],  num1); }
            if ((bits >> (dg + 16)) & 1u) { den2 += e; num2 = fmaf(e, sX[ll][dg + 16], num2); }
            if ((bits >> (dg + 24)) & 1u) { den3 += e; num3 = fmaf(e, sX[ll][dg + 24], num3); }
        }
        float* ap = attn + ((i * 8 + b) * 32 + r) * 128 + h * 32;
        ap[dg]      = num0 / den0;
        ap[dg + 8]  = num1 / den1;
        ap[dg + 16] = num2 / den2;
        ap[dg + 24] = num3 / den3;
    } else {
        float m = -1e30f;
        float num[4] = {0.f, 0.f, 0.f, 0.f}, den[4] = {0.f, 0.f, 0.f, 0.f};
        for (int l = 0; l < 512; ++l) {
            const float t = x_mark[b * 512 + l];
            const unsigned bits = obsBits[b * 512 + l];
            const bool inr = (t >= e0 && t <= e1);
            const unsigned effD = (inr ? bits : 0u) | ~av;
            if (effD == 0u) continue;
            const unsigned effN = effD & bits;
            const float* Kp = Kmat + (b * 512 + l) * 128 + h * 32;
            float a = 0.f;
            #pragma unroll
            for (int e2 = 0; e2 < 32; ++e2) a = fmaf(sQ[r][e2], Kp[e2], a);
            const float s = a * ISQ32;
            float eNew;
            if (s > m) {
                const float scale = __expf(m - s);
                #pragma unroll
                for (int jj = 0; jj < 4; ++jj) { den[jj] *= scale; num[jj] *= scale; }
                m = s;
                eNew = 1.0f;
            } else {
                eNew = __expf(s - m);
            }
            const float* xp = x + (b * 512 + l) * 32;
            #pragma unroll
            for (int jj = 0; jj < 4; ++jj) {
                const int d = dg + 8 * jj;
                if ((effD >> d) & 1u) den[jj] += eNew;
                if ((effN >> d) & 1u) num[jj] = fmaf(eNew, xp[d], num[jj]);
            }
        }
        float* ap = attn + ((i * 8 + b) * 32 + r) * 128 + h * 32;
        #pragma unroll
        for (int jj = 0; jj < 4; ++jj) ap[dg + 8 * jj] = num[jj] / den[jj];
    }
}

// ---------------------------------------------------------------------------
// K2: reprs = attn(B,32,128) @ W_out + b_out;  z[(b*32+d)][i][r] = reprs + te16(i,r)
__global__ void k_reprs(const float* __restrict__ attn,
                        const float* __restrict__ W_out,
                        const float* __restrict__ b_out,
                        float* __restrict__ z) {
    __shared__ float sA[32][129];
    const int tid = threadIdx.x;
    const int b = blockIdx.x & 7;
    const int i = blockIdx.x >> 3;
    #pragma unroll
    for (int k = 0; k < 16; ++k) {
        const int idx = tid + 256 * k;
        sA[idx >> 7][idx & 127] = attn[(i * 8 + b) * 4096 + idx];
    }
    __syncthreads();
    const int r = tid & 31, dgrp = tid >> 5;
    float acc0 = 0.f, acc1 = 0.f, acc2 = 0.f, acc3 = 0.f;
    #pragma unroll 8
    for (int k = 0; k < 128; ++k) {
        const float a = sA[r][k];
        acc0 = fmaf(a, W_out[k * 32 + dgrp],      acc0);
        acc1 = fmaf(a, W_out[k * 32 + dgrp + 8],  acc1);
        acc2 = fmaf(a, W_out[k * 32 + dgrp + 16], acc2);
        acc3 = fmaf(a, W_out[k * 32 + dgrp + 24], acc3);
    }
    const float dv = expf((float)(2 * (r >> 1)) * C32);
    const float ang = (float)i * dv;
    const float pe = (r & 1) ? cosf(ang) : sinf(ang);
    const int base = i * 32 + r;
    z[(b * 32 + dgrp)      * 512 + base] = acc0 + b_out[dgrp]      + pe;
    z[(b * 32 + dgrp + 8)  * 512 + base] = acc1 + b_out[dgrp + 8]  + pe;
    z[(b * 32 + dgrp + 16) * 512 + base] = acc2 + b_out[dgrp + 16] + pe;
    z[(b * 32 + dgrp + 24) * 512 + base] = acc3 + b_out[dgrp + 24] + pe;
}

// ---------------------------------------------------------------------------
// K3 v3: weights bulk-staged in LDS row-major, one burst per layer with
// issue-early (layer top) / ds_write-late (after FFN2) split; compute reads
// weights as conflict-free scalar LDS (lane j -> bank j), activations as
// uniform float4 broadcasts; residual stream in regs; shuffle LayerNorms.
#define QKV6(ax, bx, kk) { \
    const float wq_ = sWq[(kk) * 32 + j]; \
    const float wk_ = sWk[(kk) * 32 + j]; \
    const float wv_ = sWv[(kk) * 32 + j]; \
    qa = fmaf(ax, wq_, qa); qb = fmaf(bx, wq_, qb); \
    ka = fmaf(ax, wk_, ka); kb = fmaf(bx, wk_, kb); \
    va = fmaf(ax, wv_, va); vb = fmaf(bx, wv_, vb); }
#define OP2(ax, bx, kk) { \
    const float w_ = sWo[(kk) * 32 + j]; \
    oa = fmaf(ax, w_, oa); ob = fmaf(bx, w_, ob); }
#define F2(ax, bx, kk) { \
    const float w_ = sW2[(kk) * 32 + j]; \
    fa = fmaf(ax, w_, fa); fb = fmaf(bx, w_, fb); }

__launch_bounds__(256, 1)
__global__ void k_former(const float* __restrict__ z,
                         const float* __restrict__ f_Wq, const float* __restrict__ f_Wk,
                         const float* __restrict__ f_Wv, const float* __restrict__ f_Wo,
                         const float* __restrict__ f_bq, const float* __restrict__ f_bk,
                         const float* __restrict__ f_bv, const float* __restrict__ f_bo,
                         const float* __restrict__ f_ln1_g, const float* __restrict__ f_ln1_b,
                         const float* __restrict__ f_W1, const float* __restrict__ f_b1,
                         const float* __restrict__ f_W2, const float* __restrict__ f_b2,
                         const float* __restrict__ f_ln2_g, const float* __restrict__ f_ln2_b,
                         const float* __restrict__ ln_f_g, const float* __restrict__ ln_f_b,
                         const float* __restrict__ W_lin, const float* __restrict__ b_lin,
                         float* __restrict__ out) {
    __shared__ float sWq[1024], sWk[1024], sWv[1024], sWo[1024];
    __shared__ float sW1[4096], sW2[4096];
    __shared__ float sZ[16][32];
    __shared__ float sQs[16][33], sKs[16][33], sVs[16][33];
    __shared__ float sO[16][32];
    __shared__ float sH[16][128];
    __shared__ float sZf[512];
    __shared__ float sPart[2][96];
    const int tid = threadIdx.x;
    const int n = blockIdx.x;
    const int j = tid & 31, s2 = tid >> 5;
    const int sA = s2 * 2, sB = sA + 1;
    const int g = tid >> 6, t64 = tid & 63;
    const float* Wg = (g == 0) ? f_Wq : ((g == 1) ? f_Wk : ((g == 2) ? f_Wv : f_Wo));
    float* dstg = (g == 0) ? sWq : ((g == 1) ? sWk : ((g == 2) ? sWv : sWo));

    // initial activations
    #pragma unroll
    for (int k = 0; k < 2; ++k) {
        const int idx = tid + 256 * k;
        sZ[idx >> 5][idx & 31] = z[n * 512 + idx];
    }
    float zlocA = z[n * 512 + sA * 32 + j];
    float zlocB = z[n * 512 + sB * 32 + j];
    // prologue: stage layer-0 weights (one bulk burst)
    {
        float4 rq[4], r1[4], r2[4];
        #pragma unroll
        for (int rep = 0; rep < 4; ++rep) rq[rep] = ((const float4*)Wg)[rep * 64 + t64];
        #pragma unroll
        for (int rep = 0; rep < 4; ++rep) r1[rep] = ((const float4*)f_W1)[rep * 256 + tid];
        #pragma unroll
        for (int rep = 0; rep < 4; ++rep) r2[rep] = ((const float4*)f_W2)[rep * 256 + tid];
        #pragma unroll
        for (int rep = 0; rep < 4; ++rep) ((float4*)dstg)[rep * 64 + t64] = rq[rep];
        #pragma unroll
        for (int rep = 0; rep < 4; ++rep) ((float4*)sW1)[rep * 256 + tid] = r1[rep];
        #pragma unroll
        for (int rep = 0; rep < 4; ++rep) ((float4*)sW2)[rep * 256 + tid] = r2[rep];
    }
    __syncthreads();

    float4 nq[4], n1[4], n2[4];
    for (int layer = 0; layer < 3; ++layer) {
        // issue next-layer weight loads NOW; ds_write them after FFN2 barrier
        if (layer < 2) {
            const int offQ = (layer + 1) * 1024, offF = (layer + 1) * 4096;
            #pragma unroll
            for (int rep = 0; rep < 4; ++rep) nq[rep] = ((const float4*)(Wg + offQ))[rep * 64 + t64];
            #pragma unroll
            for (int rep = 0; rep < 4; ++rep) n1[rep] = ((const float4*)(f_W1 + offF))[rep * 256 + tid];
            #pragma unroll
            for (int rep = 0; rep < 4; ++rep) n2[rep] = ((const float4*)(f_W2 + offF))[rep * 256 + tid];
        }
        // ---- QKV ----
        {
            const float bq = f_bq[layer * 32 + j], bk = f_bk[layer * 32 + j], bv = f_bv[layer * 32 + j];
            float qa = 0.f, qb = 0.f, ka = 0.f, kb = 0.f, va = 0.f, vb = 0.f;
            const float4* zra = (const float4*)&sZ[sA][0];
            const float4* zrb = (const float4*)&sZ[sB][0];
            #pragma unroll
            for (int k4 = 0; k4 < 8; ++k4) {
                const float4 a = zra[k4], b4 = zrb[k4];
                QKV6(a.x, b4.x, 4 * k4 + 0)
                QKV6(a.y, b4.y, 4 * k4 + 1)
                QKV6(a.z, b4.z, 4 * k4 + 2)
                QKV6(a.w, b4.w, 4 * k4 + 3)
            }
            sQs[sA][j] = qa + bq; sQs[sB][j] = qb + bq;
            sKs[sA][j] = ka + bk; sKs[sB][j] = kb + bk;
            sVs[sA][j] = va + bv; sVs[sB][j] = vb + bv;
        }
        __syncthreads();
        // ---- attention: 256 threads, (head, q, e-half) ----
        {
            const int q = tid & 15, hh = (tid >> 4) & 7, half = tid >> 7;
            float sc[16];
            float mx = -1e30f;
            #pragma unroll
            for (int k = 0; k < 16; ++k) {
                float a = 0.f;
                #pragma unroll
                for (int e = 0; e < 4; ++e) a = fmaf(sQs[q][hh * 4 + e], sKs[k][hh * 4 + e], a);
                sc[k] = a * 0.5f;
                mx = fmaxf(mx, sc[k]);
            }
            float sum = 0.f;
            #pragma unroll
            for (int k = 0; k < 16; ++k) { sc[k] = __expf(sc[k] - mx); sum += sc[k]; }
            const float inv = 1.0f / sum;
            #pragma unroll
            for (int m = 0; m < 2; ++m) {
                const int e = half * 2 + m;
                float a = 0.f;
                #pragma unroll
                for (int k = 0; k < 16; ++k) a = fmaf(sc[k], sVs[k][hh * 4 + e], a);
                sO[q][hh * 4 + e] = a * inv;
            }
        }
        __syncthreads();
        // ---- O projection + residual + LN1 ----
        {
            const float bo = f_bo[layer * 32 + j];
            const float g1 = f_ln1_g[layer * 32 + j], be1 = f_ln1_b[layer * 32 + j];
            float oa = 0.f, ob = 0.f;
            const float4* ora = (const float4*)&sO[sA][0];
            const float4* orb = (const float4*)&sO[sB][0];
            #pragma unroll
            for (int k4 = 0; k4 < 8; ++k4) {
                const float4 a = ora[k4], b4 = orb[k4];
                OP2(a.x, b4.x, 4 * k4 + 0)
                OP2(a.y, b4.y, 4 * k4 + 1)
                OP2(a.z, b4.z, 4 * k4 + 2)
                OP2(a.w, b4.w, 4 * k4 + 3)
            }
            const float tA = zlocA + oa + bo, tB = zlocB + ob + bo;
            float sumA = tA, sqA = tA * tA, sumB = tB, sqB = tB * tB;
            #pragma unroll
            for (int off = 16; off > 0; off >>= 1) {
                sumA += __shfl_xor(sumA, off); sqA += __shfl_xor(sqA, off);
                sumB += __shfl_xor(sumB, off); sqB += __shfl_xor(sqB, off);
            }
            const float muA = sumA * (1.0f / 32.0f);
            const float rsA = rsqrtf(sqA * (1.0f / 32.0f) - muA * muA + 1e-5f);
            const float muB = sumB * (1.0f / 32.0f);
            const float rsB = rsqrtf(sqB * (1.0f / 32.0f) - muB * muB + 1e-5f);
            zlocA = (tA - muA) * rsA * g1 + be1;
            zlocB = (tB - muB) * rsB * g1 + be1;
            sZ[sA][j] = zlocA;
            sZ[sB][j] = zlocB;
        }
        __syncthreads();
        // ---- FFN1 + gelu ----
        {
            const int f = tid & 127, sh = tid >> 7;
            const float b1v = f_b1[layer * 128 + f];
            float w1c[32];
            #pragma unroll
            for (int k = 0; k < 32; ++k) w1c[k] = sW1[k * 128 + f];
            #pragma unroll
            for (int ss = 0; ss < 8; ++ss) {
                const int s = sh * 8 + ss;
                const float4* zr = (const float4*)&sZ[s][0];
                float acc = b1v;
                #pragma unroll
                for (int k4 = 0; k4 < 8; ++k4) {
                    const float4 a = zr[k4];
                    acc = fmaf(a.x, w1c[4 * k4], acc);     acc = fmaf(a.y, w1c[4 * k4 + 1], acc);
                    acc = fmaf(a.z, w1c[4 * k4 + 2], acc); acc = fmaf(a.w, w1c[4 * k4 + 3], acc);
                }
                const float c = acc;
                const float a2 = 1.5957691216057308f * (c + 0.044715f * c * c * c);
                const float e = __expf(a2);
                sH[s][f] = 0.5f * c * (2.0f - 2.0f / (e + 1.0f));
            }
        }
        __syncthreads();
        // ---- FFN2 + residual + LN2 ----
        {
            const float b2v = f_b2[layer * 32 + j];
            const float g2 = f_ln2_g[layer * 32 + j], be2 = f_ln2_b[layer * 32 + j];
            float fa = 0.f, fb = 0.f;
            const float4* hra = (const float4*)&sH[sA][0];
            const float4* hrb = (const float4*)&sH[sB][0];
            #pragma unroll
            for (int k4 = 0; k4 < 32; ++k4) {
                const float4 a = hra[k4], b4 = hrb[k4];
                F2(a.x, b4.x, 4 * k4 + 0)
                F2(a.y, b4.y, 4 * k4 + 1)
                F2(a.z, b4.z, 4 * k4 + 2)
                F2(a.w, b4.w, 4 * k4 + 3)
            }
            const float tA = zlocA + fa + b2v, tB = zlocB + fb + b2v;
            float sumA = tA, sqA = tA * tA, sumB = tB, sqB = tB * tB;
            #pragma unroll
            for (int off = 16; off > 0; off >>= 1) {
                sumA += __shfl_xor(sumA, off); sqA += __shfl_xor(sqA, off);
                sumB += __shfl_xor(sumB, off); sqB += __shfl_xor(sqB, off);
            }
            const float muA = sumA * (1.0f / 32.0f);
            const float rsA = rsqrtf(sqA * (1.0f / 32.0f) - muA * muA + 1e-5f);
            const float muB = sumB * (1.0f / 32.0f);
            const float rsB = rsqrtf(sqB * (1.0f / 32.0f) - muB * muB + 1e-5f);
            zlocA = (tA - muA) * rsA * g2 + be2;
            zlocB = (tB - muB) * rsB * g2 + be2;
            sZ[sA][j] = zlocA;
            sZ[sB][j] = zlocB;
        }
        __syncthreads();   // FFN2 done reading sW2/sH
        // ---- write next-layer weights (loads issued at layer top: latency hidden) ----
        if (layer < 2) {
            #pragma unroll
            for (int rep = 0; rep < 4; ++rep) ((float4*)dstg)[rep * 64 + t64] = nq[rep];
            #pragma unroll
            for (int rep = 0; rep < 4; ++rep) ((float4*)sW1)[rep * 256 + tid] = n1[rep];
            #pragma unroll
            for (int rep = 0; rep < 4; ++rep) ((float4*)sW2)[rep * 256 + tid] = n2[rep];
            __syncthreads();
        }
    }
    // ---- final LN (register stream) + transposed zf write ----
    {
        float sumA = zlocA, sqA = zlocA * zlocA, sumB = zlocB, sqB = zlocB * zlocB;
        #pragma unroll
        for (int off = 16; off > 0; off >>= 1) {
            sumA += __shfl_xor(sumA, off); sqA += __shfl_xor(sqA, off);
            sumB += __shfl_xor(sumB, off); sqB += __shfl_xor(sqB, off);
        }
        const float muA = sumA * (1.0f / 32.0f);
        const float rsA = rsqrtf(sqA * (1.0f / 32.0f) - muA * muA + 1e-5f);
        const float muB = sumB * (1.0f / 32.0f);
        const float rsB = rsqrtf(sqB * (1.0f / 32.0f) - muB * muB + 1e-5f);
        const float gf = ln_f_g[j], bf = ln_f_b[j];
        sZf[j * 16 + sA] = (zlocA - muA) * rsA * gf + bf;
        sZf[j * 16 + sB] = (zlocB - muB) * rsB * gf + bf;
    }
    __syncthreads();
    // ---- head: 2-way j-split, deep unroll for outstanding W_lin loads ----
    if (tid < 192) {
        const int half = tid / 96, o = tid % 96;
        const int j0 = half * 256;
        float acc = 0.f;
        #pragma unroll 16
        for (int jj = 0; jj < 256; ++jj)
            acc = fmaf(sZf[j0 + jj], W_lin[(j0 + jj) * 96 + o], acc);
        sPart[half][o] = acc;
    }
    __syncthreads();
    if (tid < 96)
        out[((n >> 5) * 96 + tid) * 32 + (n & 31)] = sPart[0][tid] + sPart[1][tid] + b_lin[tid];
}

// ---------------------------------------------------------------------------
extern "C" void kernel_launch(void* const* d_in, const int* in_sizes, int n_in,
                              void* d_out, int out_size, void* d_ws, size_t ws_size,
                              hipStream_t stream) {
    const float* x       = (const float*)d_in[0];
    const float* x_mark  = (const float*)d_in[1];
    const float* x_mask  = (const float*)d_in[2];
    const float* Wq      = (const float*)d_in[3];
    const float* Wk      = (const float*)d_in[4];
    const float* W_out   = (const float*)d_in[5];
    const float* b_out   = (const float*)d_in[6];
    const float* f_Wq    = (const float*)d_in[7];
    const float* f_Wk    = (const float*)d_in[8];
    const float* f_Wv    = (const float*)d_in[9];
    const float* f_Wo    = (const float*)d_in[10];
    const float* f_bq    = (const float*)d_in[11];
    const float* f_bk    = (const float*)d_in[12];
    const float* f_bv    = (const float*)d_in[13];
    const float* f_bo    = (const float*)d_in[14];
    const float* f_ln1_g = (const float*)d_in[15];
    const float* f_ln1_b = (const float*)d_in[16];
    const float* f_W1    = (const float*)d_in[17];
    const float* f_b1    = (const float*)d_in[18];
    const float* f_W2    = (const float*)d_in[19];
    const float* f_b2    = (const float*)d_in[20];
    const float* f_ln2_g = (const float*)d_in[21];
    const float* f_ln2_b = (const float*)d_in[22];
    const float* ln_f_g  = (const float*)d_in[23];
    const float* ln_f_b  = (const float*)d_in[24];
    const float* W_lin   = (const float*)d_in[25];
    const float* b_lin   = (const float*)d_in[26];

    float* ws = (float*)d_ws;
    float* Kmat      = ws;                      // 4096*128 = 524288
    float* Qall      = ws + 524288;             // 512*128  = 65536
    unsigned* obsB   = (unsigned*)(ws + 589824);// 4096 words
    float* attn      = ws + 593920;             // 16*8*32*128 = 524288
    float* zbuf      = ws + 1118208;            // 256*16*32 = 131072   (total ~5.0 MB)

    k_embed_mm<<<656, 256, 0, stream>>>(x_mark, Wk, Wq, x_mask, Kmat, Qall, obsB);
    k_patch_attn<<<512, 256, 0, stream>>>(x, x_mark, obsB, Kmat, Qall, attn);
    k_reprs<<<128, 256, 0, stream>>>(attn, W_out, b_out, zbuf);
    k_former<<<256, 256, 0, stream>>>(zbuf,
        f_Wq, f_Wk, f_Wv, f_Wo, f_bq, f_bk, f_bv, f_bo,
        f_ln1_g, f_ln1_b, f_W1, f_b1, f_W2, f_b2, f_ln2_g, f_ln2_b,
        ln_f_g, ln_f_b, W_lin, b_lin, (float*)d_out);
}

// Round 6
// 62.701 us; speedup vs baseline: 1.1615x; 1.1615x over previous
//
#include <hip/hip_runtime.h>
#include <math.h>

// Model_78271484002488: B=8, L=512, D=32, N_PATCHES=16, N_REF=32, LAT=128, HM=4,
// FH=8, NL=3, FF=128, PRED=96.  All f32.

#define ISQ32 0.17677669529663687f   // 1/sqrt(32)
#define C128  (-0.07195578415606394f)  // -ln(1e4)/128
#define C32   (-0.28782313662425575f)  // -ln(1e4)/32

// ---------------------------------------------------------------------------
// K0: blocks [0,144): embed matvec, 32 rows/block (8 rows/wave).
//     blocks [144,656): obsBits via ballot.
__launch_bounds__(256)
__global__ void k_embed_mm(const float* __restrict__ x_mark,
                           const float* __restrict__ Wk,
                           const float* __restrict__ Wq,
                           const float* __restrict__ x_mask,
                           float* __restrict__ Kmat,
                           float* __restrict__ Qall,
                           unsigned* __restrict__ obsBits) {
    if (blockIdx.x >= 144) {
        const int gt = (blockIdx.x - 144) * 256 + threadIdx.x;
        const int w = gt >> 6, lane = gt & 63;
        const int bl = w * 2 + (lane >> 5);
        const int d = lane & 31;
        const unsigned long long mm = __ballot(x_mask[bl * 32 + d] > 0.0f);
        if (lane == 0)  obsBits[w * 2]     = (unsigned)(mm & 0xffffffffull);
        if (lane == 32) obsBits[w * 2 + 1] = (unsigned)(mm >> 32);
        return;
    }
    __shared__ float sTe[32][128];
    const int wv = threadIdx.x >> 6;
    const int lane = threadIdx.x & 63;
    const int bb = blockIdx.x;
    const int row0 = bb * 32 + wv * 8;
    const float dv = __expf((float)(2 * lane) * C128);
    #pragma unroll
    for (int rr = 0; rr < 8; ++rr) {
        const int row = row0 + rr;
        const float t = (row < 4096) ? x_mark[row] : (float)(row - 4096) * (512.0f / 511.0f);
        const float ang = t * dv;
        sTe[wv * 8 + rr][2 * lane]     = __sinf(ang);
        sTe[wv * 8 + rr][2 * lane + 1] = __cosf(ang);
    }
    __syncthreads();
    const float* W = (bb < 128) ? Wk : Wq;
    float a0[8], a1[8];
    #pragma unroll
    for (int rr = 0; rr < 8; ++rr) { a0[rr] = 0.f; a1[rr] = 0.f; }
    for (int k = 0; k < 128; ++k) {
        const float wa = W[k * 128 + lane];
        const float wb = W[k * 128 + lane + 64];
        #pragma unroll
        for (int rr = 0; rr < 8; ++rr) {
            const float te = sTe[wv * 8 + rr][k];
            a0[rr] = fmaf(te, wa, a0[rr]);
            a1[rr] = fmaf(te, wb, a1[rr]);
        }
    }
    #pragma unroll
    for (int rr = 0; rr < 8; ++rr) {
        const int row = row0 + rr;
        float* outp = (row < 4096) ? (Kmat + row * 128) : (Qall + (row - 4096) * 128);
        outp[lane] = a0[rr];
        outp[lane + 64] = a1[rr];
    }
}

// ---------------------------------------------------------------------------
// K1: fused patch attention, range-based.  block = (i,b,h); 256 threads.
__launch_bounds__(256)
__global__ void k_patch_attn(const float* __restrict__ x,
                             const float* __restrict__ x_mark,
                             const unsigned* __restrict__ obsBits,
                             const float* __restrict__ Kmat,
                             const float* __restrict__ Qall,
                             float* __restrict__ attn) {
    __shared__ float sQ[32][36];
    __shared__ float sK[96][36];
    __shared__ float sX[96][36];
    __shared__ float sS[32][100];
    __shared__ unsigned sBits[96];
    __shared__ int sLo, sHi;
    __shared__ unsigned sAV;
    const int tid = threadIdx.x;
    const int h = blockIdx.x & 3;
    const int b = (blockIdx.x >> 2) & 7;
    const int i = blockIdx.x >> 5;
    const float e0 = 32.0f * (float)i, e1 = 32.0f * (float)(i + 1);
    if (tid == 0) { sLo = 512; sHi = -1; sAV = 0u; }
    __syncthreads();
    #pragma unroll
    for (int k = 0; k < 4; ++k) {
        const int idx = tid + 256 * k;
        sQ[idx >> 5][idx & 31] = Qall[(i * 32 + (idx >> 5)) * 128 + h * 32 + (idx & 31)];
    }
    {
        int mylo = 512, myhi = -1;
        unsigned mybits = 0u;
        #pragma unroll
        for (int k = 0; k < 2; ++k) {
            const int l = tid + 256 * k;
            const float t = x_mark[b * 512 + l];
            if (t >= e0 && t <= e1) {
                mylo = min(mylo, l);
                myhi = max(myhi, l);
                mybits |= obsBits[b * 512 + l];
            }
        }
        #pragma unroll
        for (int off = 32; off > 0; off >>= 1) {
            mylo = min(mylo, __shfl_xor(mylo, off));
            myhi = max(myhi, __shfl_xor(myhi, off));
            mybits |= __shfl_xor(mybits, off);
        }
        if ((tid & 63) == 0) {
            atomicMin(&sLo, mylo);
            atomicMax(&sHi, myhi);
            atomicOr(&sAV, mybits);
        }
    }
    __syncthreads();
    const int lo = sLo, hi = sHi;
    const int NA = hi - lo + 1;
    const unsigned av = sAV;
    const int r = tid >> 3, dg = tid & 7;

    if (NA >= 1 && NA <= 96 && av == 0xffffffffu) {
        if (tid < NA) sBits[tid] = obsBits[b * 512 + lo + tid];
        for (int idx = tid; idx < NA * 32; idx += 256) {
            const int ll = idx >> 5, c = idx & 31;
            sK[ll][c] = Kmat[(b * 512 + lo + ll) * 128 + h * 32 + c];
            sX[ll][c] = x[(b * 512 + lo + ll) * 32 + c];
        }
        __syncthreads();
        float m = -1e30f;
        for (int ll = dg; ll < NA; ll += 8) {
            float p0 = 0.f, p1 = 0.f, p2 = 0.f, p3 = 0.f;
            #pragma unroll
            for (int e = 0; e < 32; e += 4) {
                p0 = fmaf(sQ[r][e],     sK[ll][e],     p0);
                p1 = fmaf(sQ[r][e + 1], sK[ll][e + 1], p1);
                p2 = fmaf(sQ[r][e + 2], sK[ll][e + 2], p2);
                p3 = fmaf(sQ[r][e + 3], sK[ll][e + 3], p3);
            }
            const float s = (p0 + p1 + p2 + p3) * ISQ32;
            sS[r][ll] = s;
            m = fmaxf(m, s);
        }
        #pragma unroll
        for (int off = 4; off > 0; off >>= 1) m = fmaxf(m, __shfl_xor(m, off));
        for (int ll = dg; ll < NA; ll += 8) sS[r][ll] = __expf(sS[r][ll] - m);
        __syncthreads();
        float num0 = 0.f, num1 = 0.f, num2 = 0.f, num3 = 0.f;
        float den0 = 0.f, den1 = 0.f, den2 = 0.f, den3 = 0.f;
        for (int ll = 0; ll < NA; ++ll) {
            const float e = sS[r][ll];
            const unsigned bits = sBits[ll];
            if ((bits >> dg) & 1u)        { den0 += e; num0 = fmaf(e, sX[ll][dg],      num0); }
            if ((bits >> (dg + 8)) & 1u)  { den1 += e; num1 = fmaf(e, sX[ll][dg + 8],  num1); }
            if ((bits >> (dg + 16)) & 1u) { den2 += e; num2 = fmaf(e, sX[ll][dg + 16], num2); }
            if ((bits >> (dg + 24)) & 1u) { den3 += e; num3 = fmaf(e, sX[ll][dg + 24], num3); }
        }
        float* ap = attn + ((i * 8 + b) * 32 + r) * 128 + h * 32;
        ap[dg]      = num0 / den0;
        ap[dg + 8]  = num1 / den1;
        ap[dg + 16] = num2 / den2;
        ap[dg + 24] = num3 / den3;
    } else {
        float m = -1e30f;
        float num[4] = {0.f, 0.f, 0.f, 0.f}, den[4] = {0.f, 0.f, 0.f, 0.f};
        for (int l = 0; l < 512; ++l) {
            const float t = x_mark[b * 512 + l];
            const unsigned bits = obsBits[b * 512 + l];
            const bool inr = (t >= e0 && t <= e1);
            const unsigned effD = (inr ? bits : 0u) | ~av;
            if (effD == 0u) continue;
            const unsigned effN = effD & bits;
            const float* Kp = Kmat + (b * 512 + l) * 128 + h * 32;
            float a = 0.f;
            #pragma unroll
            for (int e2 = 0; e2 < 32; ++e2) a = fmaf(sQ[r][e2], Kp[e2], a);
            const float s = a * ISQ32;
            float eNew;
            if (s > m) {
                const float scale = __expf(m - s);
                #pragma unroll
                for (int jj = 0; jj < 4; ++jj) { den[jj] *= scale; num[jj] *= scale; }
                m = s;
                eNew = 1.0f;
            } else {
                eNew = __expf(s - m);
            }
            const float* xp = x + (b * 512 + l) * 32;
            #pragma unroll
            for (int jj = 0; jj < 4; ++jj) {
                const int d = dg + 8 * jj;
                if ((effD >> d) & 1u) den[jj] += eNew;
                if ((effN >> d) & 1u) num[jj] = fmaf(eNew, xp[d], num[jj]);
            }
        }
        float* ap = attn + ((i * 8 + b) * 32 + r) * 128 + h * 32;
        #pragma unroll
        for (int jj = 0; jj < 4; ++jj) ap[dg + 8 * jj] = num[jj] / den[jj];
    }
}

// ---------------------------------------------------------------------------
// K2: reprs = attn(B,32,128) @ W_out + b_out;  z[(b*32+d)][i][r] = reprs + te16(i,r)
__global__ void k_reprs(const float* __restrict__ attn,
                        const float* __restrict__ W_out,
                        const float* __restrict__ b_out,
                        float* __restrict__ z) {
    __shared__ float sA[32][129];
    const int tid = threadIdx.x;
    const int b = blockIdx.x & 7;
    const int i = blockIdx.x >> 3;
    #pragma unroll
    for (int k = 0; k < 16; ++k) {
        const int idx = tid + 256 * k;
        sA[idx >> 7][idx & 127] = attn[(i * 8 + b) * 4096 + idx];
    }
    __syncthreads();
    const int r = tid & 31, dgrp = tid >> 5;
    float acc0 = 0.f, acc1 = 0.f, acc2 = 0.f, acc3 = 0.f;
    #pragma unroll 8
    for (int k = 0; k < 128; ++k) {
        const float a = sA[r][k];
        acc0 = fmaf(a, W_out[k * 32 + dgrp],      acc0);
        acc1 = fmaf(a, W_out[k * 32 + dgrp + 8],  acc1);
        acc2 = fmaf(a, W_out[k * 32 + dgrp + 16], acc2);
        acc3 = fmaf(a, W_out[k * 32 + dgrp + 24], acc3);
    }
    const float dv = expf((float)(2 * (r >> 1)) * C32);
    const float ang = (float)i * dv;
    const float pe = (r & 1) ? cosf(ang) : sinf(ang);
    const int base = i * 32 + r;
    z[(b * 32 + dgrp)      * 512 + base] = acc0 + b_out[dgrp]      + pe;
    z[(b * 32 + dgrp + 8)  * 512 + base] = acc1 + b_out[dgrp + 8]  + pe;
    z[(b * 32 + dgrp + 16) * 512 + base] = acc2 + b_out[dgrp + 16] + pe;
    z[(b * 32 + dgrp + 24) * 512 + base] = acc3 + b_out[dgrp + 24] + pe;
}

// ---------------------------------------------------------------------------
// K3 v4: token-stable mapping.  Wave owns 4 tokens; 16 lanes/token; lane owns
// dims j0=2*l16, j0+1.  Only attention crosses tokens -> 9 barriers total.
// Residual rows in per-token LDS (intra-wave RAW, no barrier).  LN via 16-lane
// shuffles.  Per-layer weights in one 50KB LDS buffer (restaged per layer).
// wbuf float offsets: Wq 0, Wk 1024, Wv 2048, Wo 3072, W1t 4096 (128x36), W2 8704.
__launch_bounds__(256, 1)
__global__ void k_former(const float* __restrict__ z,
                         const float* __restrict__ f_Wq, const float* __restrict__ f_Wk,
                         const float* __restrict__ f_Wv, const float* __restrict__ f_Wo,
                         const float* __restrict__ f_bq, const float* __restrict__ f_bk,
                         const float* __restrict__ f_bv, const float* __restrict__ f_bo,
                         const float* __restrict__ f_ln1_g, const float* __restrict__ f_ln1_b,
                         const float* __restrict__ f_W1, const float* __restrict__ f_b1,
                         const float* __restrict__ f_W2, const float* __restrict__ f_b2,
                         const float* __restrict__ f_ln2_g, const float* __restrict__ f_ln2_b,
                         const float* __restrict__ ln_f_g, const float* __restrict__ ln_f_b,
                         const float* __restrict__ W_lin, const float* __restrict__ b_lin,
                         float* __restrict__ out) {
    __shared__ float wbuf[12800];
    __shared__ float sKmat[16][36], sVmat[16][36];
    __shared__ float sZrow[16][36], sOrow[16][36];
    __shared__ float sH[16][132];
    const int tid = threadIdx.x;
    const int n = blockIdx.x;
    const int lane64 = tid & 63;
    const int w = tid >> 6;
    const int sLoc = lane64 >> 4;
    const int s = w * 4 + sLoc;
    const int l16 = lane64 & 15;
    const int j0 = 2 * l16;
    const int gbase = lane64 & 48;   // first lane of this 16-lane token group

    // ---- weight staging (layer l) ----
    #define STAGE_LAYER(l) { \
        ((float4*)wbuf)[tid]       = ((const float4*)(f_Wq + (l) * 1024))[tid]; \
        ((float4*)wbuf)[256 + tid] = ((const float4*)(f_Wk + (l) * 1024))[tid]; \
        ((float4*)wbuf)[512 + tid] = ((const float4*)(f_Wv + (l) * 1024))[tid]; \
        ((float4*)wbuf)[768 + tid] = ((const float4*)(f_Wo + (l) * 1024))[tid]; \
        _Pragma("unroll") \
        for (int r2 = 0; r2 < 4; ++r2) { \
            const int idx4 = r2 * 256 + tid; \
            const int kk = idx4 >> 5, f4 = (idx4 & 31) << 2; \
            const float4 v = ((const float4*)(f_W1 + (l) * 4096))[idx4]; \
            wbuf[4096 + (f4 + 0) * 36 + kk] = v.x; \
            wbuf[4096 + (f4 + 1) * 36 + kk] = v.y; \
            wbuf[4096 + (f4 + 2) * 36 + kk] = v.z; \
            wbuf[4096 + (f4 + 3) * 36 + kk] = v.w; \
        } \
        _Pragma("unroll") \
        for (int r2 = 0; r2 < 4; ++r2) \
            ((float4*)(wbuf + 8704))[r2 * 256 + tid] = ((const float4*)(f_W2 + (l) * 4096))[r2 * 256 + tid]; \
    }

    // ---- prologue: initial activations + layer-0 weights ----
    {
        const int ps = tid >> 4, pj = (tid & 15) * 2;
        *(float2*)&sZrow[ps][pj] = *(const float2*)(z + n * 512 + ps * 32 + pj);
    }
    STAGE_LAYER(0)
    __syncthreads();   // barrier 1

    for (int l = 0; l < 3; ++l) {
        // ================= QKV (token-local; weights LDS; Q in regs) =========
        float q0, q1;
        {
            float4 zr[8];
            #pragma unroll
            for (int k4 = 0; k4 < 8; ++k4) zr[k4] = *(const float4*)&sZrow[s][4 * k4];
            const float2 bq = *(const float2*)(f_bq + l * 32 + j0);
            const float2 bk = *(const float2*)(f_bk + l * 32 + j0);
            const float2 bv = *(const float2*)(f_bv + l * 32 + j0);
            float qa = 0.f, qb = 0.f, ka = 0.f, kb = 0.f, va = 0.f, vb = 0.f;
            #pragma unroll
            for (int k4 = 0; k4 < 8; ++k4) {
                #pragma unroll
                for (int e = 0; e < 4; ++e) {
                    const int kk = 4 * k4 + e;
                    const float zz = (e == 0) ? zr[k4].x : (e == 1) ? zr[k4].y : (e == 2) ? zr[k4].z : zr[k4].w;
                    const float2 wq = *(const float2*)&wbuf[kk * 32 + j0];
                    const float2 wk2 = *(const float2*)&wbuf[1024 + kk * 32 + j0];
                    const float2 wv2 = *(const float2*)&wbuf[2048 + kk * 32 + j0];
                    qa = fmaf(zz, wq.x, qa);  qb = fmaf(zz, wq.y, qb);
                    ka = fmaf(zz, wk2.x, ka); kb = fmaf(zz, wk2.y, kb);
                    va = fmaf(zz, wv2.x, va); vb = fmaf(zz, wv2.y, vb);
                }
            }
            q0 = qa + bq.x; q1 = qb + bq.y;
            *(float2*)&sKmat[s][j0] = make_float2(ka + bk.x, kb + bk.y);
            *(float2*)&sVmat[s][j0] = make_float2(va + bv.x, vb + bv.y);
        }
        __syncthreads();   // K/V of all tokens ready
        // ================= attention (own token q; all K/V) ==================
        {
            const int hh = l16 & 7, kh = l16 >> 3;
            const int h4 = hh * 4;
            const float qa = __shfl(q0, gbase + 2 * hh);
            const float qb = __shfl(q1, gbase + 2 * hh);
            const float qc = __shfl(q0, gbase + 2 * hh + 1);
            const float qd = __shfl(q1, gbase + 2 * hh + 1);
            float sc[8];
            #pragma unroll
            for (int m = 0; m < 8; ++m) {
                const int kk = kh * 8 + m;
                const float4 kv = *(const float4*)&sKmat[kk][h4];
                sc[m] = (qa * kv.x + qb * kv.y + qc * kv.z + qd * kv.w) * 0.5f;
            }
            float mx = sc[0];
            #pragma unroll
            for (int m = 1; m < 8; ++m) mx = fmaxf(mx, sc[m]);
            mx = fmaxf(mx, __shfl_xor(mx, 8));
            float sum = 0.f;
            #pragma unroll
            for (int m = 0; m < 8; ++m) { sc[m] = __expf(sc[m] - mx); sum += sc[m]; }
            sum += __shfl_xor(sum, 8);
            const float inv = 1.0f / sum;
            float o0 = 0.f, o1 = 0.f, o2 = 0.f, o3 = 0.f;
            #pragma unroll
            for (int m = 0; m < 8; ++m) {
                const int kk = kh * 8 + m;
                const float4 vv = *(const float4*)&sVmat[kk][h4];
                o0 = fmaf(sc[m], vv.x, o0); o1 = fmaf(sc[m], vv.y, o1);
                o2 = fmaf(sc[m], vv.z, o2); o3 = fmaf(sc[m], vv.w, o3);
            }
            o0 += __shfl_xor(o0, 8); o1 += __shfl_xor(o1, 8);
            o2 += __shfl_xor(o2, 8); o3 += __shfl_xor(o3, 8);
            if (kh == 0)
                *(float4*)&sOrow[s][h4] = make_float4(o0 * inv, o1 * inv, o2 * inv, o3 * inv);
        }
        // ================= O-proj + residual + LN1 (token-local) =============
        {
            float oacc0 = 0.f, oacc1 = 0.f;
            #pragma unroll
            for (int k4 = 0; k4 < 8; ++k4) {
                const float4 ov = *(const float4*)&sOrow[s][4 * k4];
                #pragma unroll
                for (int e = 0; e < 4; ++e) {
                    const float oe = (e == 0) ? ov.x : (e == 1) ? ov.y : (e == 2) ? ov.z : ov.w;
                    const float2 wo = *(const float2*)&wbuf[3072 + (4 * k4 + e) * 32 + j0];
                    oacc0 = fmaf(oe, wo.x, oacc0); oacc1 = fmaf(oe, wo.y, oacc1);
                }
            }
            const float2 bo = *(const float2*)(f_bo + l * 32 + j0);
            const float2 zold = *(const float2*)&sZrow[s][j0];
            const float t0 = zold.x + oacc0 + bo.x;
            const float t1 = zold.y + oacc1 + bo.y;
            float sm = t0 + t1, sq = t0 * t0 + t1 * t1;
            #pragma unroll
            for (int off = 8; off > 0; off >>= 1) { sm += __shfl_xor(sm, off); sq += __shfl_xor(sq, off); }
            const float mu = sm * (1.0f / 32.0f);
            const float rs = rsqrtf(sq * (1.0f / 32.0f) - mu * mu + 1e-5f);
            const float2 g1 = *(const float2*)(f_ln1_g + l * 32 + j0);
            const float2 be1 = *(const float2*)(f_ln1_b + l * 32 + j0);
            *(float2*)&sZrow[s][j0] = make_float2((t0 - mu) * rs * g1.x + be1.x,
                                                  (t1 - mu) * rs * g1.y + be1.y);
        }
        // ================= FFN1 + gelu (token-local) =========================
        {
            float4 zr[8];
            #pragma unroll
            for (int k4 = 0; k4 < 8; ++k4) zr[k4] = *(const float4*)&sZrow[s][4 * k4];
            #pragma unroll
            for (int m = 0; m < 8; ++m) {
                const int f = l16 + 16 * m;
                float acc = f_b1[l * 128 + f];
                #pragma unroll
                for (int k4 = 0; k4 < 8; ++k4) {
                    const float4 w14 = *(const float4*)&wbuf[4096 + f * 36 + 4 * k4];
                    acc = fmaf(zr[k4].x, w14.x, acc); acc = fmaf(zr[k4].y, w14.y, acc);
                    acc = fmaf(zr[k4].z, w14.z, acc); acc = fmaf(zr[k4].w, w14.w, acc);
                }
                const float c = acc;
                const float a2 = 1.5957691216057308f * (c + 0.044715f * c * c * c);
                const float e = __expf(a2);
                sH[s][f] = 0.5f * c * (2.0f - 2.0f / (e + 1.0f));
            }
        }
        // ================= FFN2 + residual + LN2 (token-local) ===============
        {
            const float2 b2v = *(const float2*)(f_b2 + l * 32 + j0);
            float fa = 0.f, fb = 0.f;
            #pragma unroll
            for (int f4 = 0; f4 < 32; ++f4) {
                const float4 hv = *(const float4*)&sH[s][4 * f4];
                #pragma unroll
                for (int e = 0; e < 4; ++e) {
                    const float he = (e == 0) ? hv.x : (e == 1) ? hv.y : (e == 2) ? hv.z : hv.w;
                    const float2 w2 = *(const float2*)&wbuf[8704 + (4 * f4 + e) * 32 + j0];
                    fa = fmaf(he, w2.x, fa); fb = fmaf(he, w2.y, fb);
                }
            }
            const float2 zold = *(const float2*)&sZrow[s][j0];
            const float t0 = zold.x + fa + b2v.x;
            const float t1 = zold.y + fb + b2v.y;
            float sm = t0 + t1, sq = t0 * t0 + t1 * t1;
            #pragma unroll
            for (int off = 8; off > 0; off >>= 1) { sm += __shfl_xor(sm, off); sq += __shfl_xor(sq, off); }
            const float mu = sm * (1.0f / 32.0f);
            const float rs = rsqrtf(sq * (1.0f / 32.0f) - mu * mu + 1e-5f);
            const float2 g2 = *(const float2*)(f_ln2_g + l * 32 + j0);
            const float2 be2 = *(const float2*)(f_ln2_b + l * 32 + j0);
            *(float2*)&sZrow[s][j0] = make_float2((t0 - mu) * rs * g2.x + be2.x,
                                                  (t1 - mu) * rs * g2.y + be2.y);
        }
        if (l < 2) {
            __syncthreads();           // all reads of wbuf done
            if (l == 0) STAGE_LAYER(1) else STAGE_LAYER(2)
            __syncthreads();           // staging complete before next QKV
        }
    }
    // ================= final LN (token-local) ================================
    {
        const float2 zv = *(const float2*)&sZrow[s][j0];
        const float t0 = zv.x, t1 = zv.y;
        float sm = t0 + t1, sq = t0 * t0 + t1 * t1;
        #pragma unroll
        for (int off = 8; off > 0; off >>= 1) { sm += __shfl_xor(sm, off); sq += __shfl_xor(sq, off); }
        const float mu = sm * (1.0f / 32.0f);
        const float rs = rsqrtf(sq * (1.0f / 32.0f) - mu * mu + 1e-5f);
        const float2 gf = *(const float2*)(ln_f_g + j0);
        const float2 bf = *(const float2*)(ln_f_b + j0);
        *(float2*)&sZrow[s][j0] = make_float2((t0 - mu) * rs * gf.x + bf.x,
                                              (t1 - mu) * rs * gf.y + bf.y);
    }
    // ================= head: partial over own token row ======================
    {
        float* sRed = &sH[0][0];   // alias (FFN use finished; intra-wave order ok)
        float4 zr[8];
        #pragma unroll
        for (int k4 = 0; k4 < 8; ++k4) zr[k4] = *(const float4*)&sZrow[s][4 * k4];
        const int o0 = 6 * l16;
        float p0 = 0.f, p1 = 0.f, p2 = 0.f, p3 = 0.f, p4 = 0.f, p5 = 0.f;
        #pragma unroll
        for (int k4 = 0; k4 < 8; ++k4) {
            #pragma unroll
            for (int e = 0; e < 4; ++e) {
                const int rr = 4 * k4 + e;
                const float zz = (e == 0) ? zr[k4].x : (e == 1) ? zr[k4].y : (e == 2) ? zr[k4].z : zr[k4].w;
                const float* wl = W_lin + (rr * 16 + s) * 96 + o0;
                const float2 wa = *(const float2*)(wl);
                const float2 wb = *(const float2*)(wl + 2);
                const float2 wc = *(const float2*)(wl + 4);
                p0 = fmaf(zz, wa.x, p0); p1 = fmaf(zz, wa.y, p1);
                p2 = fmaf(zz, wb.x, p2); p3 = fmaf(zz, wb.y, p3);
                p4 = fmaf(zz, wc.x, p4); p5 = fmaf(zz, wc.y, p5);
            }
        }
        *(float2*)&sRed[s * 100 + o0]     = make_float2(p0, p1);
        *(float2*)&sRed[s * 100 + o0 + 2] = make_float2(p2, p3);
        *(float2*)&sRed[s * 100 + o0 + 4] = make_float2(p4, p5);
    }
    __syncthreads();   // cross-wave reduce
    if (tid < 96) {
        const float* sRed = &sH[0][0];
        float acc = b_lin[tid];
        #pragma unroll
        for (int ss = 0; ss < 16; ++ss) acc += sRed[ss * 100 + tid];
        out[((n >> 5) * 96 + tid) * 32 + (n & 31)] = acc;
    }
}

// ---------------------------------------------------------------------------
extern "C" void kernel_launch(void* const* d_in, const int* in_sizes, int n_in,
                              void* d_out, int out_size, void* d_ws, size_t ws_size,
                              hipStream_t stream) {
    const float* x       = (const float*)d_in[0];
    const float* x_mark  = (const float*)d_in[1];
    const float* x_mask  = (const float*)d_in[2];
    const float* Wq      = (const float*)d_in[3];
    const float* Wk      = (const float*)d_in[4];
    const float* W_out   = (const float*)d_in[5];
    const float* b_out   = (const float*)d_in[6];
    const float* f_Wq    = (const float*)d_in[7];
    const float* f_Wk    = (const float*)d_in[8];
    const float* f_Wv    = (const float*)d_in[9];
    const float* f_Wo    = (const float*)d_in[10];
    const float* f_bq    = (const float*)d_in[11];
    const float* f_bk    = (const float*)d_in[12];
    const float* f_bv    = (const float*)d_in[13];
    const float* f_bo    = (const float*)d_in[14];
    const float* f_ln1_g = (const float*)d_in[15];
    const float* f_ln1_b = (const float*)d_in[16];
    const float* f_W1    = (const float*)d_in[17];
    const float* f_b1    = (const float*)d_in[18];
    const float* f_W2    = (const float*)d_in[19];
    const float* f_b2    = (const float*)d_in[20];
    const float* f_ln2_g = (const float*)d_in[21];
    const float* f_ln2_b = (const float*)d_in[22];
    const float* ln_f_g  = (const float*)d_in[23];
    const float* ln_f_b  = (const float*)d_in[24];
    const float* W_lin   = (const float*)d_in[25];
    const float* b_lin   = (const float*)d_in[26];

    float* ws = (float*)d_ws;
    float* Kmat      = ws;                      // 4096*128 = 524288
    float* Qall      = ws + 524288;             // 512*128  = 65536
    unsigned* obsB   = (unsigned*)(ws + 589824);// 4096 words
    float* attn      = ws + 593920;             // 16*8*32*128 = 524288
    float* zbuf      = ws + 1118208;            // 256*16*32 = 131072   (total ~5.0 MB)

    k_embed_mm<<<656, 256, 0, stream>>>(x_mark, Wk, Wq, x_mask, Kmat, Qall, obsB);
    k_patch_attn<<<512, 256, 0, stream>>>(x, x_mark, obsB, Kmat, Qall, attn);
    k_reprs<<<128, 256, 0, stream>>>(attn, W_out, b_out, zbuf);
    k_former<<<256, 256, 0, stream>>>(zbuf,
        f_Wq, f_Wk, f_Wv, f_Wo, f_bq, f_bk, f_bv, f_bo,
        f_ln1_g, f_ln1_b, f_W1, f_b1, f_W2, f_b2, f_ln2_g, f_ln2_b,
        ln_f_g, ln_f_b, W_lin, b_lin, (float*)d_out);
}